// Round 4
// baseline (335.259 us; speedup 1.0000x reference)
//
#include <hip/hip_runtime.h>

#define B_ 4
#define T_ 4096
#define DM 512
#define DH 64
#define CS 512     // s-chunk for k_out
#define CT 512     // t-chunk for k_stats

typedef short short8 __attribute__((ext_vector_type(8)));
typedef float f32x4 __attribute__((ext_vector_type(4)));
typedef float float8 __attribute__((ext_vector_type(8)));

__device__ inline short f2bf(float f) {
    unsigned u = __float_as_uint(f);
    u += 0x7fffu + ((u >> 16) & 1u);
    return (short)(u >> 16);
}
__device__ inline float bf2f(short s) {
    return __uint_as_float(((unsigned)(unsigned short)s) << 16);
}
__device__ inline short8 cvt8(const float* p) {
    float8 v = *(const float8*)p;
    short8 r;
#pragma unroll
    for (int j = 0; j < 8; j++) r[j] = f2bf(v[j]);
    return r;
}

// ---------------- Kernel 0: x -> bf16 xb, and Wq|Wk|Wv -> bf16 wb ----------------
// grid = 4144 blocks: first 4096 cover x (8.4M elems), last 48 cover W (98304 elems)
__global__ __launch_bounds__(256) void k_cvt(
    const float* __restrict__ x, const float* __restrict__ Wq,
    const float* __restrict__ Wk, const float* __restrict__ Wv,
    short* __restrict__ xb, short* __restrict__ wb)
{
    long e = ((long)blockIdx.x * 256 + threadIdx.x) * 8;
    const long NX = (long)B_ * T_ * DM;  // 8388608
    if (e < NX) {
        *(short8*)(xb + e) = cvt8(x + e);
    } else {
        long o = e - NX;
        int m = (int)(o / (DH * DM));
        int off = (int)(o - (long)m * (DH * DM));
        const float* W = (m == 0) ? Wq : (m == 1) ? Wk : Wv;
        *(short8*)(wb + (long)m * DH * DM + off) = cvt8(W + off);
    }
}

// ---------------- Kernel 1: q,k,v projections (bf16 x, h-split 2x) ----------------
// grid = 6 * 256; blockIdx: r = bi & 255 (row-tile), mh = bi >> 8 (m*2+hh)
__global__ __launch_bounds__(256) void k_proj(
    const short* __restrict__ xb, const short* __restrict__ wb,
    short* __restrict__ qb, short* __restrict__ kb, short* __restrict__ vb)
{
    int tid = threadIdx.x;
    int lane = tid & 63, w = tid >> 6;
    int l16 = lane & 15, quad = lane >> 4;
    int r = blockIdx.x & 255;
    int mh = blockIdx.x >> 8;
    int m = mh >> 1, hh = mh & 1;
    int b = r >> 6, tile = r & 63;
    int t0w = tile * 64 + w * 16;
    long base_x = ((long)(b * T_ + t0w + l16)) * DM;
    const short* W = wb + m * DH * DM;
    short* outp = (m == 0) ? qb : (m == 1) ? kb : vb;
    int h0 = hh * 32 + l16;

    f32x4 acc0 = (f32x4)(0.f), acc1 = (f32x4)(0.f);
    for (int kc = 0; kc < DM; kc += 32) {
        short8 af = *(const short8*)(xb + base_x + kc + quad * 8);   // A[m=t][k=d]
        short8 b0 = *(const short8*)(W + (long)h0 * DM + kc + quad * 8);
        short8 b1 = *(const short8*)(W + (long)(h0 + 16) * DM + kc + quad * 8);
        acc0 = __builtin_amdgcn_mfma_f32_16x16x32_bf16(af, b0, acc0, 0, 0, 0);
        acc1 = __builtin_amdgcn_mfma_f32_16x16x32_bf16(af, b1, acc1, 0, 0, 0);
    }
#pragma unroll
    for (int r4 = 0; r4 < 4; r4++) {
        long o = ((long)(b * T_ + t0w + quad * 4 + r4)) * DH;
        outp[o + hh * 32 + l16] = f2bf(acc0[r4]);
        outp[o + hh * 32 + 16 + l16] = f2bf(acc1[r4]);
    }
}

// ---------------- Kernel 2: partial column sums l[s] += sum_{t in chunk, t>=s} exp(z) ----------------
// grid = B * 64 * (T/CT); barrier-free, direct global frag loads
__global__ __launch_bounds__(256) void k_stats(
    const short* __restrict__ qb, const short* __restrict__ kb, float* __restrict__ lsum)
{
    int tid = threadIdx.x;
    int lane = tid & 63, w = tid >> 6;
    int l16 = lane & 15, quad = lane >> 4;
    const int NC = T_ / CT;   // 8
    int chunk = blockIdx.x % NC;
    int st64 = (blockIdx.x / NC) & 63;
    int b = blockIdx.x / (NC * 64);
    int c0 = chunk * CT;
    int lim = c0 + CT;
    int s0blk = st64 * 64;
    if (lim <= s0blk) return;
    int s0w = s0blk + w * 16;
    int tb0 = (c0 > s0w) ? c0 : s0w;   // multiple of 16
    long bq = (long)b * T_ * DH;

    const short8* ka = (const short8*)(kb + bq + (long)(s0w + l16) * DH + quad * 8);
    short8 a0 = ka[0], a1 = ka[4];     // A[m=s][k=h]

    float acc[4] = {0.f, 0.f, 0.f, 0.f};
    const float SC = 0.125f;
    for (int tb = tb0; tb < lim; tb += 16) {
        const short8* qp = (const short8*)(qb + bq + (long)(tb + l16) * DH + quad * 8);
        short8 b0 = qp[0], b1 = qp[4];
        f32x4 d = (f32x4)(0.f);
        d = __builtin_amdgcn_mfma_f32_16x16x32_bf16(a0, b0, d, 0, 0, 0);
        d = __builtin_amdgcn_mfma_f32_16x16x32_bf16(a1, b1, d, 0, 0, 0);
        int t = tb + l16;              // D: row=s (quad*4+r), col=t (l16)
#pragma unroll
        for (int r = 0; r < 4; r++) {
            int s = s0w + quad * 4 + r;
            float p = __expf(d[r] * SC);
            acc[r] += (t >= s) ? p : 0.f;
        }
    }
#pragma unroll
    for (int r = 0; r < 4; r++) {
        float v = acc[r];
        v += __shfl_xor(v, 1, 16);
        v += __shfl_xor(v, 2, 16);
        v += __shfl_xor(v, 4, 16);
        v += __shfl_xor(v, 8, 16);
        if (l16 == 0) atomicAdd(&lsum[b * T_ + s0w + quad * 4 + r], v);
    }
}

// ---------------- Kernel 3: vT[b][h][s] = bf16(v[b][s][h] / l[s]) ----------------
__global__ __launch_bounds__(256) void k_vt(
    const short* __restrict__ vb, const float* __restrict__ lsum, short* __restrict__ vT)
{
    __shared__ float tile[64][65];
    int tid = threadIdx.x;
    int b = blockIdx.x >> 6;
    int s0 = (blockIdx.x & 63) * 64;
    int h = tid & 63;
#pragma unroll
    for (int i = 0; i < 16; i++) {
        int s = (tid >> 6) + i * 4;
        tile[s][h] = bf2f(vb[((long)(b * T_ + s0 + s)) * DH + h]);
    }
    __syncthreads();
    int sl = tid & 63;
    float rl = 1.0f / lsum[b * T_ + s0 + sl];
    long ob = (long)b * DH * T_ + s0 + sl;
#pragma unroll
    for (int i = 0; i < 16; i++) {
        int hh = (tid >> 6) + i * 4;
        vT[ob + (long)hh * T_] = f2bf(tile[sl][hh] * rl);
    }
}

// ---------------- Kernel 4: barrier-free pipelined score+PV ----------------
// grid = B * 64 * (T/CS); double-buffered wave-private P tile; atomics into out
__global__ __launch_bounds__(256) void k_out(
    const short* __restrict__ qb, const short* __restrict__ kb,
    const short* __restrict__ vT, float* __restrict__ out)
{
    __shared__ short Pt[4][2][16 * 40];   // wave-private double-buffered P tiles (10 KB)
    int tid = threadIdx.x;
    int lane = tid & 63, w = tid >> 6;
    int l16 = lane & 15, quad = lane >> 4;
    const int NC = T_ / CS;   // 8
    int chunk = blockIdx.x % NC;
    int rt = (blockIdx.x / NC) & 63;
    int b = blockIdx.x / (NC * 64);
    int c0 = chunk * CS;
    if (c0 > rt * 64 + 63) return;
    int t0w = rt * 64 + w * 16;
    int tmax = t0w + 15;
    int s_end = (c0 + CS < tmax + 1) ? c0 + CS : tmax + 1;
    int nsub = (s_end - c0 + 31) >> 5;   // >= 1 (c0 <= rt*64 <= t0w)
    long bq = (long)b * T_ * DH;
    long vbase = (long)b * DH * T_;
    const float SC = 0.125f;

    const short8* qp = (const short8*)(qb + bq + (long)(t0w + l16) * DH + quad * 8);
    short8 aq0 = qp[0], aq1 = qp[4];     // A[m=t][k=h]

    f32x4 o[4];
#pragma unroll
    for (int i = 0; i < 4; i++) o[i] = (f32x4)(0.f);
    short* pb0 = (short*)Pt[w][0];
    short* pb1 = (short*)Pt[w][1];
    short8 vf[4];

    // QK + exp + store P-tile for s-cols [sc, sc+32) into dst
    auto qk_store = [&](int sc, short* dst) {
#pragma unroll
        for (int sh = 0; sh < 2; sh++) {
            int s0h = sc + sh * 16;
            if (s0h < s_end) {
                const short8* kp = (const short8*)(kb + bq + (long)(s0h + l16) * DH + quad * 8);
                short8 kb0 = kp[0], kb1 = kp[4];
                f32x4 d = (f32x4)(0.f);
                d = __builtin_amdgcn_mfma_f32_16x16x32_bf16(aq0, kb0, d, 0, 0, 0);
                d = __builtin_amdgcn_mfma_f32_16x16x32_bf16(aq1, kb1, d, 0, 0, 0);
                int s = s0h + l16;       // D: row=t (quad*4+r), col=s (l16)
#pragma unroll
                for (int r = 0; r < 4; r++) {
                    int t = t0w + quad * 4 + r;
                    float p = __expf(d[r] * SC);
                    p = (s <= t) ? p : 0.f;
                    dst[(quad * 4 + r) * 40 + sh * 16 + l16] = f2bf(p);
                }
            } else {
#pragma unroll
                for (int r = 0; r < 4; r++)
                    dst[(quad * 4 + r) * 40 + sh * 16 + l16] = 0;
            }
        }
    };
    auto vload = [&](int sc) {
#pragma unroll
        for (int h4 = 0; h4 < 4; h4++)
            vf[h4] = *(const short8*)(vT + vbase + (long)(h4 * 16 + l16) * T_ + sc + quad * 8);
    };

    // prologue: sub 0
    qk_store(c0, pb0);
    vload(c0);
    // pipelined main loop: PV of sub j-1 overlapped with QK of sub j
    for (int j = 1; j < nsub; j++) {
        short* prev = ((j - 1) & 1) ? pb1 : pb0;
        short8 ap = *(const short8*)(prev + l16 * 40 + quad * 8);   // A[m=t][k=s_local]
#pragma unroll
        for (int h4 = 0; h4 < 4; h4++)
            o[h4] = __builtin_amdgcn_mfma_f32_16x16x32_bf16(ap, vf[h4], o[h4], 0, 0, 0);
        int sc = c0 + j * 32;
        qk_store(sc, (j & 1) ? pb1 : pb0);
        vload(sc);
    }
    // drain last sub
    {
        short* prev = ((nsub - 1) & 1) ? pb1 : pb0;
        short8 ap = *(const short8*)(prev + l16 * 40 + quad * 8);
#pragma unroll
        for (int h4 = 0; h4 < 4; h4++)
            o[h4] = __builtin_amdgcn_mfma_f32_16x16x32_bf16(ap, vf[h4], o[h4], 0, 0, 0);
    }

#pragma unroll
    for (int h4 = 0; h4 < 4; h4++)
#pragma unroll
        for (int r = 0; r < 4; r++) {
            int t = t0w + quad * 4 + r;
            atomicAdd(&out[bq + (long)t * DH + h4 * 16 + l16], o[h4][r]);
        }
}

extern "C" void kernel_launch(void* const* d_in, const int* in_sizes, int n_in,
                              void* d_out, int out_size, void* d_ws, size_t ws_size,
                              hipStream_t stream) {
    const float* x  = (const float*)d_in[0];
    const float* Wq = (const float*)d_in[1];
    const float* Wk = (const float*)d_in[2];
    const float* Wv = (const float*)d_in[3];
    float* out = (float*)d_out;

    char* ws = (char*)d_ws;
    short* qb   = (short*)(ws);                    // 2 MB  bf16 [B,T,64]
    short* kb   = (short*)(ws + (2l << 20));       // 2 MB  bf16 [B,T,64]
    short* vb   = (short*)(ws + (4l << 20));       // 2 MB  bf16 [B,T,64]
    short* vT   = (short*)(ws + (6l << 20));       // 2 MB  bf16 [B,64,T]
    short* wb   = (short*)(ws + (8l << 20));       // 192 KB bf16 [3,64,512]
    float* lsum = (float*)(ws + (9l << 20));       // 64 KB fp32 [B,T]
    short* xb   = (short*)(ws + (10l << 20));      // 16 MB bf16 [B,T,512]

    hipMemsetAsync(out, 0, (size_t)out_size * sizeof(float), stream);
    hipMemsetAsync(lsum, 0, (size_t)(B_ * T_) * sizeof(float), stream);

    k_cvt<<<dim3(4144), dim3(256), 0, stream>>>(x, Wq, Wk, Wv, xb, wb);
    k_proj<<<dim3(6 * 256), dim3(256), 0, stream>>>(xb, wb, qb, kb, vb);
    k_stats<<<dim3(B_ * 64 * (T_ / CT)), dim3(256), 0, stream>>>(qb, kb, lsum);
    k_vt<<<dim3(B_ * T_ / 64), dim3(256), 0, stream>>>(vb, lsum, vT);
    k_out<<<dim3(B_ * 64 * (T_ / CS)), dim3(256), 0, stream>>>(qb, kb, vT, out);
}

// Round 6
// 205.435 us; speedup vs baseline: 1.6319x; 1.6319x over previous
//
#include <hip/hip_runtime.h>

#define B_ 4
#define T_ 4096
#define DM 512
#define DH 64
#define CS 512     // s-chunk for k_out (per rt128 tile: rt/4+1 chunks)
#define CT 512     // t-chunk for k_stats

typedef short short8 __attribute__((ext_vector_type(8)));
typedef short bsh4 __attribute__((ext_vector_type(4)));
typedef float f32x4 __attribute__((ext_vector_type(4)));
typedef float float8 __attribute__((ext_vector_type(8)));

__device__ inline short f2bf(float f) {
    unsigned u = __float_as_uint(f);
    u += 0x7fffu + ((u >> 16) & 1u);
    return (short)(u >> 16);
}
__device__ inline float bf2f(short s) {
    return __uint_as_float(((unsigned)(unsigned short)s) << 16);
}
__device__ inline short8 cvt8s(const float* p, float sc) {
    float8 v = *(const float8*)p;
    short8 r;
#pragma unroll
    for (int j = 0; j < 8; j++) r[j] = f2bf(v[j] * sc);
    return r;
}

// 16x16x16 bf16 MFMA (PV): A = per-lane P frag, B = vT frag
__device__ inline f32x4 mfma16(bsh4 a, bsh4 b, f32x4 c) {
    return __builtin_amdgcn_mfma_f32_16x16x16bf16_1k(a, b, c, 0, 0, 0);
}

// ---------------- Kernel 0: Wq|Wk|Wv (fp32) -> wb (bf16, concat); Wq scaled by 0.125 ----------------
__global__ __launch_bounds__(256) void k_wcvt(
    const float* __restrict__ Wq, const float* __restrict__ Wk,
    const float* __restrict__ Wv, short* __restrict__ wb)
{
    int e = (blockIdx.x * 256 + threadIdx.x) * 8;
    int m = e / (DH * DM);
    int off = e - m * (DH * DM);
    const float* W = (m == 0) ? Wq : (m == 1) ? Wk : Wv;
    float sc = (m == 0) ? 0.125f : 1.0f;
    *(short8*)(wb + e) = cvt8s(W + off, sc);
}

// ---------------- Kernel 1: q,k,v projections; x read once, staged bf16 in LDS ----------------
// grid = B*T/32 = 512 blocks; block covers 32 rows; each wave: 48 of 192 output cols
__global__ __launch_bounds__(256) void k_proj(
    const float* __restrict__ x, const short* __restrict__ wb,
    short* __restrict__ qb, short* __restrict__ kb, short* __restrict__ vb)
{
    __shared__ short xs[32 * 520];   // 32 rows x (512+8) bf16
    int tid = threadIdx.x;
    int lane = tid & 63, w = tid >> 6;
    int l16 = lane & 15, quad = lane >> 4;
    long R0 = (long)blockIdx.x * 32;

    // stage x tile (fp32 -> bf16), coalesced
#pragma unroll
    for (int p = 0; p < 8; p++) {
        int idx = p * 256 + tid;
        int row = idx >> 6, colc = idx & 63;
        *(short8*)(xs + row * 520 + colc * 8) = cvt8s(x + (R0 + row) * DM + colc * 8, 1.0f);
    }
    __syncthreads();

    int cb = w * 48;
    const short* Wrow[3];
    int mm[3], hc[3];
#pragma unroll
    for (int i = 0; i < 3; i++) {
        int col0 = cb + i * 16;
        mm[i] = col0 >> 6;
        hc[i] = (col0 & 63) + l16;
        Wrow[i] = wb + mm[i] * DH * DM + (long)hc[i] * DM;
    }

    f32x4 a0[3], a1[3];
#pragma unroll
    for (int i = 0; i < 3; i++) { a0[i] = (f32x4)(0.f); a1[i] = (f32x4)(0.f); }

    for (int kc = 0; kc < DM; kc += 32) {
        short8 af0 = *(const short8*)(xs + l16 * 520 + kc + quad * 8);
        short8 af1 = *(const short8*)(xs + (16 + l16) * 520 + kc + quad * 8);
#pragma unroll
        for (int i = 0; i < 3; i++) {
            short8 bf = *(const short8*)(Wrow[i] + kc + quad * 8);
            a0[i] = __builtin_amdgcn_mfma_f32_16x16x32_bf16(af0, bf, a0[i], 0, 0, 0);
            a1[i] = __builtin_amdgcn_mfma_f32_16x16x32_bf16(af1, bf, a1[i], 0, 0, 0);
        }
    }
#pragma unroll
    for (int i = 0; i < 3; i++) {
        short* op = (mm[i] == 0) ? qb : (mm[i] == 1) ? kb : vb;
#pragma unroll
        for (int r4 = 0; r4 < 4; r4++) {
            long t0 = R0 + quad * 4 + r4;
            op[t0 * DH + hc[i]] = f2bf(a0[i][r4]);
            op[(t0 + 16) * DH + hc[i]] = f2bf(a1[i][r4]);
        }
    }
}

// ---------------- Kernel 2: column sums l[s] += sum_{t in chunk, t>=s} exp(z) ----------------
// dense balanced grid: 4 * 288 blocks; block = 64 s-rows x 512-t chunk; no barriers
__global__ __launch_bounds__(256) void k_stats(
    const short* __restrict__ qb, const short* __restrict__ kb, float* __restrict__ lsum)
{
    int tid = threadIdx.x;
    int lane = tid & 63, w = tid >> 6;
    int l16 = lane & 15, quad = lane >> 4;
    int b = blockIdx.x / 288;
    int idx = blockIdx.x % 288;
    int st = 0, rem = idx;
    while (true) { int n = 8 - (st >> 3); if (rem < n) break; rem -= n; st++; }
    int chunk = (st >> 3) + rem;
    int c0 = chunk * CT, lim = c0 + CT;
    int s0w = st * 64 + w * 16;
    int tb0 = (c0 > (s0w & ~31)) ? c0 : (s0w & ~31);
    long bq = (long)b * T_ * DH;

    const short8* ka = (const short8*)(kb + bq + (long)(s0w + l16) * DH + quad * 8);
    short8 ka0 = ka[0], ka1 = ka[4];   // A[m=s][k=h]

    float acc[4] = {0.f, 0.f, 0.f, 0.f};
    // prefetch current Q frags (t rows tb+l16 / tb+16+l16)
    const short* qbase = qb + bq;
    short8 qA0 = *(const short8*)(qbase + (long)(tb0 + l16) * DH + quad * 8);
    short8 qA1 = *(const short8*)(qbase + (long)(tb0 + l16) * DH + 32 + quad * 8);
    short8 qB0 = *(const short8*)(qbase + (long)(tb0 + 16 + l16) * DH + quad * 8);
    short8 qB1 = *(const short8*)(qbase + (long)(tb0 + 16 + l16) * DH + 32 + quad * 8);

    for (int tb = tb0; tb < lim; tb += 32) {
        int tn = (tb + 32 < lim) ? tb + 32 : tb0;   // safe prefetch addr
        short8 nA0 = *(const short8*)(qbase + (long)(tn + l16) * DH + quad * 8);
        short8 nA1 = *(const short8*)(qbase + (long)(tn + l16) * DH + 32 + quad * 8);
        short8 nB0 = *(const short8*)(qbase + (long)(tn + 16 + l16) * DH + quad * 8);
        short8 nB1 = *(const short8*)(qbase + (long)(tn + 16 + l16) * DH + 32 + quad * 8);

        f32x4 dA = (f32x4)(0.f), dB = (f32x4)(0.f);
        dA = __builtin_amdgcn_mfma_f32_16x16x32_bf16(ka0, qA0, dA, 0, 0, 0);
        dA = __builtin_amdgcn_mfma_f32_16x16x32_bf16(ka1, qA1, dA, 0, 0, 0);
        dB = __builtin_amdgcn_mfma_f32_16x16x32_bf16(ka0, qB0, dB, 0, 0, 0);
        dB = __builtin_amdgcn_mfma_f32_16x16x32_bf16(ka1, qB1, dB, 0, 0, 0);
        int tA = tb + l16, tB = tb + 16 + l16;
#pragma unroll
        for (int r = 0; r < 4; r++) {
            int s = s0w + quad * 4 + r;
            float pA = __expf(dA[r]);
            float pB = __expf(dB[r]);
            acc[r] += ((tA >= s) ? pA : 0.f) + ((tB >= s) ? pB : 0.f);
        }
        qA0 = nA0; qA1 = nA1; qB0 = nB0; qB1 = nB1;
    }
#pragma unroll
    for (int r = 0; r < 4; r++) {
        float v = acc[r];
        v += __shfl_xor(v, 1, 16);
        v += __shfl_xor(v, 2, 16);
        v += __shfl_xor(v, 4, 16);
        v += __shfl_xor(v, 8, 16);
        if (l16 == 0) atomicAdd(&lsum[b * T_ + s0w + quad * 4 + r], v);
    }
}

// ---------------- Kernel 3: vT[b][h][s] = bf16(v[b][s][h] / l[s]) ----------------
__global__ __launch_bounds__(256) void k_vt(
    const short* __restrict__ vb, const float* __restrict__ lsum, short* __restrict__ vT)
{
    __shared__ float tile[64][65];
    int tid = threadIdx.x;
    int b = blockIdx.x >> 6;
    int s0 = (blockIdx.x & 63) * 64;
    int h = tid & 63;
#pragma unroll
    for (int i = 0; i < 16; i++) {
        int s = (tid >> 6) + i * 4;
        tile[s][h] = bf2f(vb[((long)(b * T_ + s0 + s)) * DH + h]);
    }
    __syncthreads();
    int sl = tid & 63;
    float rl = 1.0f / lsum[b * T_ + s0 + sl];
    long ob = (long)b * DH * T_ + s0 + sl;
#pragma unroll
    for (int i = 0; i < 16; i++) {
        int hh = (tid >> 6) + i * 4;
        vT[ob + (long)hh * T_] = f2bf(tile[sl][hh] * rl);
    }
}

// ---------------- Kernel 4: transposed-QK fused score+PV; zero LDS, zero barriers ----------------
// dense balanced grid: 4 * 144 blocks (rt descending = heavy first)
// block covers 128 t-rows (wave: 32), chunk of CS s-cols; atomics into out
__global__ __launch_bounds__(256) void k_out(
    const short* __restrict__ qb, const short* __restrict__ kb,
    const short* __restrict__ vT, float* __restrict__ out)
{
    int tid = threadIdx.x;
    int lane = tid & 63, w = tid >> 6;
    int l16 = lane & 15, quad = lane >> 4;
    int b = blockIdx.x / 144;
    int idx = blockIdx.x % 144;
    int rt = 31, rem = idx;
    while (true) { int n = (rt >> 2) + 1; if (rem < n) break; rem -= n; rt--; }
    int c0 = rem * CS;
    int t0w = rt * 128 + w * 32;                 // wave's 32 t-rows
    int s_end = (c0 + CS < t0w + 32) ? c0 + CS : t0w + 32;
    if (s_end <= c0) return;                     // wave idle (no barriers -> safe)
    int nsub = (s_end - c0 + 15) >> 4;
    long bq = (long)b * T_ * DH;
    long vbase = (long)b * DH * T_;

    const short* qbase = qb + bq;
    short8 aqA0 = *(const short8*)(qbase + (long)(t0w + l16) * DH + quad * 8);
    short8 aqA1 = *(const short8*)(qbase + (long)(t0w + l16) * DH + 32 + quad * 8);
    short8 aqB0 = *(const short8*)(qbase + (long)(t0w + 16 + l16) * DH + quad * 8);
    short8 aqB1 = *(const short8*)(qbase + (long)(t0w + 16 + l16) * DH + 32 + quad * 8);

    f32x4 oA[4], oB[4];
#pragma unroll
    for (int i = 0; i < 4; i++) { oA[i] = (f32x4)(0.f); oB[i] = (f32x4)(0.f); }

    const short* kbase = kb + bq;
    // current frags
    short8 kc0 = *(const short8*)(kbase + (long)(c0 + l16) * DH + quad * 8);
    short8 kc1 = *(const short8*)(kbase + (long)(c0 + l16) * DH + 32 + quad * 8);
    bsh4 vc[4];
#pragma unroll
    for (int h4 = 0; h4 < 4; h4++)
        vc[h4] = *(const bsh4*)(vT + vbase + (long)(h4 * 16 + l16) * T_ + c0 + quad * 4);

    int tA = t0w + l16, tB = t0w + 16 + l16;
    for (int j = 0; j < nsub; j++) {
        int sp = (j + 1 < nsub) ? c0 + (j + 1) * 16 : c0;   // safe prefetch addr
        short8 kn0 = *(const short8*)(kbase + (long)(sp + l16) * DH + quad * 8);
        short8 kn1 = *(const short8*)(kbase + (long)(sp + l16) * DH + 32 + quad * 8);
        bsh4 vn[4];
#pragma unroll
        for (int h4 = 0; h4 < 4; h4++)
            vn[h4] = *(const bsh4*)(vT + vbase + (long)(h4 * 16 + l16) * T_ + sp + quad * 4);

        int s0 = c0 + j * 16;
        f32x4 dA = (f32x4)(0.f), dB = (f32x4)(0.f);
        dA = __builtin_amdgcn_mfma_f32_16x16x32_bf16(kc0, aqA0, dA, 0, 0, 0);
        dA = __builtin_amdgcn_mfma_f32_16x16x32_bf16(kc1, aqA1, dA, 0, 0, 0);
        dB = __builtin_amdgcn_mfma_f32_16x16x32_bf16(kc0, aqB0, dB, 0, 0, 0);
        dB = __builtin_amdgcn_mfma_f32_16x16x32_bf16(kc1, aqB1, dB, 0, 0, 0);

        // D[s][t]: lane holds s = s0+quad*4+r, t = l16 (+16 for group B)
        // == exactly the A-operand frag of mfma_f32_16x16x16: m=t=l16, k=s=quad*4+j
        bsh4 fA, fB;
        int sb = s0 + quad * 4;
#pragma unroll
        for (int r = 0; r < 4; r++) {
            int s = sb + r;
            float pA = __expf(dA[r]);
            float pB = __expf(dB[r]);
            fA[r] = f2bf((s <= tA) ? pA : 0.f);
            fB[r] = f2bf((s <= tB) ? pB : 0.f);
        }
#pragma unroll
        for (int h4 = 0; h4 < 4; h4++) {
            oA[h4] = mfma16(fA, vc[h4], oA[h4]);
            oB[h4] = mfma16(fB, vc[h4], oB[h4]);
        }
        kc0 = kn0; kc1 = kn1;
#pragma unroll
        for (int h4 = 0; h4 < 4; h4++) vc[h4] = vn[h4];
    }

#pragma unroll
    for (int h4 = 0; h4 < 4; h4++)
#pragma unroll
        for (int r = 0; r < 4; r++) {
            atomicAdd(&out[bq + (long)(t0w + quad * 4 + r) * DH + h4 * 16 + l16], oA[h4][r]);
            atomicAdd(&out[bq + (long)(t0w + 16 + quad * 4 + r) * DH + h4 * 16 + l16], oB[h4][r]);
        }
}

extern "C" void kernel_launch(void* const* d_in, const int* in_sizes, int n_in,
                              void* d_out, int out_size, void* d_ws, size_t ws_size,
                              hipStream_t stream) {
    const float* x  = (const float*)d_in[0];
    const float* Wq = (const float*)d_in[1];
    const float* Wk = (const float*)d_in[2];
    const float* Wv = (const float*)d_in[3];
    float* out = (float*)d_out;

    char* ws = (char*)d_ws;
    short* qb   = (short*)(ws);                    // 2 MB  bf16 [B,T,64]  (q pre-scaled by 0.125)
    short* kb   = (short*)(ws + (2l << 20));       // 2 MB  bf16 [B,T,64]
    short* vb   = (short*)(ws + (4l << 20));       // 2 MB  bf16 [B,T,64]
    short* vT   = (short*)(ws + (6l << 20));       // 2 MB  bf16 [B,64,T]  (v/l, transposed)
    short* wb   = (short*)(ws + (8l << 20));       // 192 KB bf16 [3,64,512]
    float* lsum = (float*)(ws + (9l << 20));       // 64 KB fp32 [B,T]

    (void)hipMemsetAsync(out, 0, (size_t)out_size * sizeof(float), stream);
    (void)hipMemsetAsync(lsum, 0, (size_t)(B_ * T_) * sizeof(float), stream);

    k_wcvt<<<dim3(48), dim3(256), 0, stream>>>(Wq, Wk, Wv, wb);
    k_proj<<<dim3(B_ * T_ / 32), dim3(256), 0, stream>>>(x, wb, qb, kb, vb);
    k_stats<<<dim3(4 * 288), dim3(256), 0, stream>>>(qb, kb, lsum);
    k_vt<<<dim3(B_ * T_ / 64), dim3(256), 0, stream>>>(vb, lsum, vT);
    k_out<<<dim3(4 * 144), dim3(256), 0, stream>>>(qb, kb, vT, out);
}